// Round 1
// baseline (255.175 us; speedup 1.0000x reference)
//
#include <hip/hip_runtime.h>

// 3-level a-trous B3-spline UWT, fully fused in one kernel.
// Tile 60x60 output, halo 14 each side (2*(1+2+4)), 88x88 staged in LDS.
// Two LDS buffers ping-pong the separable H-conv / W-conv per level.
// Reflect symmetry: conv(sym kernel) of reflect-extension == reflect-extension
// of conv, so halo values computed from reflected input are exact for all levels.

constexpr int TILE = 60;
constexpr int RAD  = 14;
constexpr int IN   = TILE + 2 * RAD;   // 88
constexpr int LS   = IN + 1;           // 89, LDS row stride (conflict padding)
constexpr int IMG_H = 1024;
constexpr int IMG_W = 1024;
constexpr int NTX = (IMG_W + TILE - 1) / TILE;  // 18
constexpr int NTY = (IMG_H + TILE - 1) / TILE;  // 18
constexpr int NTHREADS = 256;

constexpr float TAP0 = 1.0f / 16.0f;   // taps at +/-2d
constexpr float TAP1 = 1.0f / 4.0f;    // taps at +/-1d
constexpr float TAP2 = 3.0f / 8.0f;    // center tap

// One wavelet level: H-conv (A -> Bs) then W-conv (Bs -> A) with fused
// w_J = c_{J-1} - c_J store. D = dilation; input valid region is
// [AIN, IN-AIN)^2 in A; output valid region [AOUT, IN-AOUT)^2 (AOUT = AIN+2D).
template <int D, int AIN, int AOUT, int J>
__device__ __forceinline__ void process_level(float* A, float* Bs, int tid,
                                              int b, int oy0, int ox0,
                                              float* __restrict__ out) {
    constexpr int NR = IN - 2 * AOUT;  // rows produced
    constexpr int NC = IN - 2 * AIN;   // cols carried through H-conv

    // --- conv along H: Bs[r][c] = sum_k w[k] * A[r + (k-2)*D][c]
    for (int i = tid; i < NR * NC; i += NTHREADS) {
        int q = i / NC;
        int r = AOUT + q;
        int c = AIN + (i - q * NC);
        const float* p = A + r * LS + c;
        Bs[r * LS + c] = TAP0 * (p[-2 * D * LS] + p[2 * D * LS]) +
                         TAP1 * (p[-D * LS] + p[D * LS]) +
                         TAP2 * p[0];
    }
    __syncthreads();

    // --- conv along W: c_J = conv(Bs); store w_J = c_{J-1} - c_J; A <- c_J
    for (int i = tid; i < NR * NR; i += NTHREADS) {
        int q = i / NR;
        int r = AOUT + q;
        int c = AOUT + (i - q * NR);
        const float* p = Bs + r * LS + c;
        float v = TAP0 * (p[-2 * D] + p[2 * D]) +
                  TAP1 * (p[-D] + p[D]) +
                  TAP2 * p[0];
        float prev = A[r * LS + c];   // c_{J-1} at this position
        if (J != 2) A[r * LS + c] = v;  // carry c_J to next level
        int ly = r - RAD, lx = c - RAD;
        if ((unsigned)ly < (unsigned)TILE && (unsigned)lx < (unsigned)TILE) {
            int oy = oy0 + ly, ox = ox0 + lx;
            if (oy < IMG_H && ox < IMG_W) {
                size_t o = ((size_t)(b * 4 + J) * IMG_H + oy) * IMG_W + ox;
                out[o] = prev - v;
                if (J == 2) {
                    out[((size_t)(b * 4 + 3) * IMG_H + oy) * IMG_W + ox] = v;
                }
            }
        }
    }
    __syncthreads();
}

__global__ __launch_bounds__(NTHREADS, 2)
void uwt3_kernel(const float* __restrict__ x, float* __restrict__ out) {
    __shared__ float A[IN * LS];   // 88*89*4 = 31328 B
    __shared__ float Bs[IN * LS];  // total 62656 B -> 2 blocks/CU

    const int tid = threadIdx.x;
    const int tile = blockIdx.x % (NTX * NTY);
    const int b    = blockIdx.x / (NTX * NTY);
    const int ty = tile / NTX;
    const int tx = tile - ty * NTX;
    const int oy0 = ty * TILE;
    const int ox0 = tx * TILE;

    const float* xb = x + (size_t)b * IMG_H * IMG_W;

    // Stage input tile with reflect halo into A.
    for (int i = tid; i < IN * IN; i += NTHREADS) {
        int r = i / IN;
        int c = i - r * IN;
        int gy = oy0 - RAD + r;
        gy = (gy < 0) ? -gy : gy;
        gy = (gy >= IMG_H) ? 2 * IMG_H - 2 - gy : gy;
        int gx = ox0 - RAD + c;
        gx = (gx < 0) ? -gx : gx;
        gx = (gx >= IMG_W) ? 2 * IMG_W - 2 - gx : gx;
        A[r * LS + c] = xb[(size_t)gy * IMG_W + gx];
    }
    __syncthreads();

    process_level<1, 0, 2, 0>(A, Bs, tid, b, oy0, ox0, out);   // d=1, w1
    process_level<2, 2, 6, 1>(A, Bs, tid, b, oy0, ox0, out);   // d=2, w2
    process_level<4, 6, 14, 2>(A, Bs, tid, b, oy0, ox0, out);  // d=4, w3 + c3
}

extern "C" void kernel_launch(void* const* d_in, const int* in_sizes, int n_in,
                              void* d_out, int out_size, void* d_ws, size_t ws_size,
                              hipStream_t stream) {
    const float* x = (const float*)d_in[0];
    float* out = (float*)d_out;
    const int nb = in_sizes[0] / (IMG_H * IMG_W);  // 8
    dim3 grid(nb * NTX * NTY);                     // 2592 blocks
    uwt3_kernel<<<grid, NTHREADS, 0, stream>>>(x, out);
}

// Round 2
// 188.696 us; speedup vs baseline: 1.3523x; 1.3523x over previous
//
#include <hip/hip_runtime.h>

#define DEVINL __device__ __forceinline__

// 3-level a-trous B3-spline UWT, fused single kernel.
// Tile: 32x72 output, staged 64x104 (halo 16 >= 14, chosen for 16B alignment).
// pack = tid&15 owns 4 consecutive cols (float4); ty = tid>>4 walks rows.
// Per level: vertical conv via 5x ds_read_b128, horizontal conv via DPP
// row_shr/row_shl (16 packs == one 16-lane DPP row, edges align with halo).
// LDS ping-pong A<->B, 53 KB total -> 3 blocks/CU.

constexpr int W_IMG = 1024;
constexpr int H_IMG = 1024;
constexpr int TX = 32;                    // output cols per tile
constexpr int TY = 72;                    // output rows per tile
constexpr int HALO = 16;                  // >= 2*(1+2+4)=14
constexpr int SW = 64;                    // staged width (floats)
constexpr int SH = TY + 2 * HALO;         // 104 staged rows
constexpr int GXT = W_IMG / TX;           // 32
constexpr int GYT = (H_IMG + TY - 1) / TY;// 15

constexpr float TP0 = 1.0f / 16.0f;
constexpr float TP1 = 1.0f / 4.0f;
constexpr float TP2 = 3.0f / 8.0f;

// DPP cross-lane fetch within 16-lane rows. row_shr:n (0x110|n) = value from
// lane i-n; row_shl:n (0x100|n) = value from lane i+n. bound_ctrl=1 -> 0 at
// row edges (lands only in halo columns, never consumed by valid outputs).
template <int CTRL>
DEVINL float dppf(float x) {
    return __int_as_float(__builtin_amdgcn_update_dpp(
        0, __float_as_int(x), CTRL, 0xF, 0xF, true));
}

DEVINL int reflx(int g) {
    g = g < 0 ? -g : g;
    return g >= W_IMG ? 2 * W_IMG - 2 - g : g;
}

template <int D, int R0, int R1, int LVL, bool LAST>
DEVINL void do_level(const float* src, float* dst, float* __restrict__ out,
                     int b4, int oy0, int gx0, int p, int ty) {
    const int c4 = p * 4;
    constexpr int KMAX = (R1 - R0 + 15) / 16;
#pragma unroll
    for (int k = 0; k < KMAX; ++k) {
        const int r = R0 + ty + 16 * k;
        if (r < R1) {  // uniform across each 16-lane DPP row (same ty)
            const float4 a0 = *(const float4*)&src[(r - 2 * D) * SW + c4];
            const float4 a1 = *(const float4*)&src[(r - D) * SW + c4];
            const float4 a2 = *(const float4*)&src[r * SW + c4];
            const float4 a3 = *(const float4*)&src[(r + D) * SW + c4];
            const float4 a4 = *(const float4*)&src[(r + 2 * D) * SW + c4];
            // vertical 5-tap
            float4 v;
            v.x = TP0 * (a0.x + a4.x) + TP1 * (a1.x + a3.x) + TP2 * a2.x;
            v.y = TP0 * (a0.y + a4.y) + TP1 * (a1.y + a3.y) + TP2 * a2.y;
            v.z = TP0 * (a0.z + a4.z) + TP1 * (a1.z + a3.z) + TP2 * a2.z;
            v.w = TP0 * (a0.w + a4.w) + TP1 * (a1.w + a3.w) + TP2 * a2.w;
            // horizontal 5-tap via DPP neighbor exchange
            float4 u;
            if constexpr (D == 1) {
                const float am2 = dppf<0x111>(v.z);  // col-2 for comp0
                const float am1 = dppf<0x111>(v.w);  // col-1 for comp0
                const float ap1 = dppf<0x101>(v.x);  // col+1 for comp3
                const float ap2 = dppf<0x101>(v.y);  // col+2 for comp3
                u.x = TP0 * (am2 + v.z) + TP1 * (am1 + v.y) + TP2 * v.x;
                u.y = TP0 * (am1 + v.w) + TP1 * (v.x + v.z) + TP2 * v.y;
                u.z = TP0 * (v.x + ap1) + TP1 * (v.y + v.w) + TP2 * v.z;
                u.w = TP0 * (v.y + ap2) + TP1 * (v.z + ap1) + TP2 * v.w;
            } else if constexpr (D == 2) {
                float4 am, ap;
                am.x = dppf<0x111>(v.x); am.y = dppf<0x111>(v.y);
                am.z = dppf<0x111>(v.z); am.w = dppf<0x111>(v.w);
                ap.x = dppf<0x101>(v.x); ap.y = dppf<0x101>(v.y);
                ap.z = dppf<0x101>(v.z); ap.w = dppf<0x101>(v.w);
                u.x = TP0 * (am.x + ap.x) + TP1 * (am.z + v.z) + TP2 * v.x;
                u.y = TP0 * (am.y + ap.y) + TP1 * (am.w + v.w) + TP2 * v.y;
                u.z = TP0 * (am.z + ap.z) + TP1 * (v.x + ap.x) + TP2 * v.z;
                u.w = TP0 * (am.w + ap.w) + TP1 * (v.y + ap.y) + TP2 * v.w;
            } else {  // D == 4: pure per-component, +/-1 and +/-2 lanes
                float4 am, ap, bm, bp;
                am.x = dppf<0x111>(v.x); am.y = dppf<0x111>(v.y);
                am.z = dppf<0x111>(v.z); am.w = dppf<0x111>(v.w);
                ap.x = dppf<0x101>(v.x); ap.y = dppf<0x101>(v.y);
                ap.z = dppf<0x101>(v.z); ap.w = dppf<0x101>(v.w);
                bm.x = dppf<0x112>(v.x); bm.y = dppf<0x112>(v.y);
                bm.z = dppf<0x112>(v.z); bm.w = dppf<0x112>(v.w);
                bp.x = dppf<0x102>(v.x); bp.y = dppf<0x102>(v.y);
                bp.z = dppf<0x102>(v.z); bp.w = dppf<0x102>(v.w);
                u.x = TP0 * (bm.x + bp.x) + TP1 * (am.x + ap.x) + TP2 * v.x;
                u.y = TP0 * (bm.y + bp.y) + TP1 * (am.y + ap.y) + TP2 * v.y;
                u.z = TP0 * (bm.z + bp.z) + TP1 * (am.z + ap.z) + TP2 * v.z;
                u.w = TP0 * (bm.w + bp.w) + TP1 * (am.w + ap.w) + TP2 * v.w;
            }
            // w_LVL = c_{LVL-1} - c_LVL ; a2 is the center (prev) value
            const int ly = r - HALO;
            const int oy = oy0 + ly;
            if ((unsigned)ly < (unsigned)TY && oy < H_IMG && p >= 4 && p < 12) {
                const int ox = gx0 + c4 - HALO;
                float4 w;
                w.x = a2.x - u.x; w.y = a2.y - u.y;
                w.z = a2.z - u.z; w.w = a2.w - u.w;
                const size_t base =
                    ((size_t)(b4 + LVL) * H_IMG + oy) * W_IMG + ox;
                *(float4*)&out[base] = w;
                if constexpr (LAST) {
                    const size_t base3 =
                        ((size_t)(b4 + 3) * H_IMG + oy) * W_IMG + ox;
                    *(float4*)&out[base3] = u;  // c_3
                }
            }
            if constexpr (!LAST) *(float4*)&dst[r * SW + c4] = u;
        }
    }
}

__global__ __launch_bounds__(256, 3) void uwt3(const float* __restrict__ x,
                                               float* __restrict__ out) {
    __shared__ __align__(16) float A[SH * SW];  // 26624 B
    __shared__ __align__(16) float B[SH * SW];  // total 53248 B -> 3 blk/CU

    const int tid = threadIdx.x;
    const int p = tid & 15;
    const int ty = tid >> 4;
    int bid = blockIdx.x;
    const int bx = bid & 31;  bid >>= 5;      // GXT = 32 (pow2)
    const int by = bid % GYT;
    const int b = bid / GYT;
    const int oy0 = by * TY;
    const int gx0 = bx * TX;
    const float* xb = x + (size_t)b * (H_IMG * W_IMG);
    const int c4 = p * 4;
    const bool edge = (bx == 0) || (bx == GXT - 1);

    // stage 64x104 input tile with reflect halo
#pragma unroll
    for (int k = 0; k < (SH + 15) / 16; ++k) {
        const int sr = ty + 16 * k;
        if (sr < SH) {
            int gy = oy0 - HALO + sr;
            gy = gy < 0 ? -gy : gy;
            if (gy >= H_IMG) gy = 2 * H_IMG - 2 - gy;
            const float* row = xb + (size_t)gy * W_IMG;
            const int gx = gx0 - HALO + c4;
            float4 v;
            if (!edge) {
                v = *(const float4*)(row + gx);
            } else {
                v.x = row[reflx(gx)];
                v.y = row[reflx(gx + 1)];
                v.z = row[reflx(gx + 2)];
                v.w = row[reflx(gx + 3)];
            }
            *(float4*)&A[sr * SW + c4] = v;
        }
    }
    __syncthreads();

    do_level<1, 2, 102, 0, false>(A, B, out, b * 4, oy0, gx0, p, ty);
    __syncthreads();
    do_level<2, 6, 98, 1, false>(B, A, out, b * 4, oy0, gx0, p, ty);
    __syncthreads();
    do_level<4, 14, 90, 2, true>(A, B, out, b * 4, oy0, gx0, p, ty);
}

extern "C" void kernel_launch(void* const* d_in, const int* in_sizes, int n_in,
                              void* d_out, int out_size, void* d_ws,
                              size_t ws_size, hipStream_t stream) {
    const float* x = (const float*)d_in[0];
    float* out = (float*)d_out;
    const int nb = in_sizes[0] / (H_IMG * W_IMG);  // 8
    dim3 grid(nb * GYT * GXT);                     // 8*15*32 = 3840
    uwt3<<<grid, 256, 0, stream>>>(x, out);
}